// Round 4
// baseline (376.735 us; speedup 1.0000x reference)
//
#include <hip/hip_runtime.h>
#include <hip/hip_bf16.h>
#include <stdint.h>

// Problem: feats[8,1024,32,32]f32, conv_w[256,1024]f32, conv_b[256]f32,
// codebook[16384,256]f32 -> z_q[8,256,32,32]f32 (2097152) + loss scalar.
//
// Round-4 design:
//  - KP=288 (256 data + col256 = bias-fold + 31 pad)
//  - gemm2 restructured: zb(B) resident in LDS (one barrier), cb2(A) streamed
//    global->register, barrier-free j-stream, argmax folded in-register
//  - loss from packed best score: dist_i = ||z_i||^2 - 2*score_i

typedef float f32x4 __attribute__((ext_vector_type(4)));
typedef short s16x8 __attribute__((ext_vector_type(8)));

#define KP 288            // padded K for gemm2 operands
#define SCALE 4194304.0f  // 2^22

__device__ __forceinline__ void gl2lds16(const void* g, void* l) {
  __builtin_amdgcn_global_load_lds(
      (const __attribute__((address_space(1))) void*)g,
      (__attribute__((address_space(3))) void*)l, 16, 0, 0);
}

__device__ __forceinline__ unsigned short f2bf(float f) {
  unsigned u = __float_as_uint(f);
  u = u + 0x7FFFu + ((u >> 16) & 1u);
  return (unsigned short)(u >> 16);
}
__device__ __forceinline__ float bf2f(unsigned short u) {
  return __uint_as_float(((unsigned)u) << 16);
}

// Fused prep. Blocks [0,16384): codebook -> cb2 bf16 [16384][288], col256 =
// -0.5||e||^2, 257..287 = 0; zb pad cols for rows<8192 (col256=1.0, rest 0).
// [16384,16640): conv_w -> W2. [16640,24832): feats transpose -> featsT.
__global__ void k_prep(const float* __restrict__ cbk, const float* __restrict__ Wsrc,
                       const float* __restrict__ feats,
                       unsigned short* __restrict__ cb2, unsigned short* __restrict__ W2,
                       unsigned short* __restrict__ At, unsigned short* __restrict__ zb,
                       float* __restrict__ lossw) {
  __shared__ float tile[32][33];
  __shared__ float ps[4];
  int blk = blockIdx.x, t = threadIdx.x;
  if (blk == 0 && t < 2) ((int*)lossw)[t] = 0;
  if (blk < 16384) {
    int j = blk;
    float v = cbk[(size_t)j * 256 + t];
    cb2[(size_t)j * KP + t] = f2bf(v);
    float s = v * v;
    #pragma unroll
    for (int m = 32; m; m >>= 1) s += __shfl_down(s, m, 64);
    if ((t & 63) == 0) ps[t >> 6] = s;
    __syncthreads();
    if (t == 0) cb2[(size_t)j * KP + 256] = f2bf(-0.5f * (ps[0] + ps[1] + ps[2] + ps[3]));
    if (t >= 1 && t < 32) cb2[(size_t)j * KP + 256 + t] = 0;
    if (j < 8192) {
      if (t == 0) zb[(size_t)j * KP + 256] = 0x3F80;  // 1.0 bf16
      if (t >= 1 && t < 32) zb[(size_t)j * KP + 256 + t] = 0;
    }
  } else if (blk < 16640) {
    int e = blk - 16384;
    #pragma unroll
    for (int k = 0; k < 4; ++k) {
      int c = t + k * 256;
      W2[(size_t)e * 1024 + c] = f2bf(Wsrc[(size_t)e * 1024 + c]);
    }
  } else {
    int id = blk - 16640;
    int b = id >> 10, c0 = ((id >> 5) & 31) * 32, s0 = (id & 31) * 32;
    int tc = t >> 5, ts = t & 31;
    #pragma unroll
    for (int k = 0; k < 4; ++k)
      tile[tc + k * 8][ts] = feats[((size_t)b * 1024 + c0 + tc + k * 8) * 1024 + s0 + ts];
    __syncthreads();
    #pragma unroll
    for (int k = 0; k < 4; ++k) {
      int sr = tc + k * 8, cw = ts;
      At[(size_t)(b * 1024 + s0 + sr) * 1024 + c0 + cw] = f2bf(tile[cw][sr]);
    }
  }
}

// GEMM1: z[i][e] = sum_c feats[i][c]*W[e][c] + b[e] (K=1024 bf16) -> zb [i][288].
// BM=BN=64, 4 waves 2x2 (wave 32x32), grid (4,128)
__global__ __launch_bounds__(256, 2)
void k_gemm1(const unsigned short* __restrict__ At, const unsigned short* __restrict__ Bw,
             const float* __restrict__ bias, unsigned short* __restrict__ zb) {
  __shared__ __align__(16) uint8_t lds[1024 * 16];
  uint8_t* ldsA = lds;
  uint8_t* ldsB = lds + 512 * 16;
  const int t = threadIdx.x, w = t >> 6, l = t & 63;
  const int wy = w >> 1, wx = w & 1, l15 = l & 15, q = l >> 4;
  const int ib = blockIdx.y * 64, eb = blockIdx.x * 64;
  f32x4 acc[2][2] = {};
  for (int kt = 0; kt < 16; ++kt) {
    int c0 = kt * 64;
    __syncthreads();
    #pragma unroll
    for (int r = 0; r < 2; ++r) {
      int P = t + 256 * r;  // kp = P>>6, m = P&63; LDS layout [kp][m]
      gl2lds16(At + (size_t)(ib + (P & 63)) * 1024 + c0 + (P >> 6) * 8, ldsA + P * 16);
    }
    #pragma unroll
    for (int r = 0; r < 2; ++r) {
      int P = t + 256 * r;
      gl2lds16(Bw + (size_t)(eb + (P & 63)) * 1024 + c0 + (P >> 6) * 8, ldsB + P * 16);
    }
    __syncthreads();
    #pragma unroll
    for (int s = 0; s < 2; ++s) {
      s16x8 a[2], b[2];
      #pragma unroll
      for (int fr = 0; fr < 2; ++fr)
        a[fr] = *(const s16x8*)(ldsA + ((s * 4 + q) * 64 + wy * 32 + fr * 16 + l15) * 16);
      #pragma unroll
      for (int fc = 0; fc < 2; ++fc)
        b[fc] = *(const s16x8*)(ldsB + ((s * 4 + q) * 64 + wx * 32 + fc * 16 + l15) * 16);
      #pragma unroll
      for (int fr = 0; fr < 2; ++fr)
        #pragma unroll
        for (int fc = 0; fc < 2; ++fc)
          acc[fr][fc] = __builtin_amdgcn_mfma_f32_16x16x32_bf16(a[fr], b[fc], acc[fr][fc], 0, 0, 0);
    }
  }
  #pragma unroll
  for (int fc = 0; fc < 2; ++fc) {
    int e = eb + wx * 32 + fc * 16 + l15;
    float bv = bias[e];
    #pragma unroll
    for (int fr = 0; fr < 2; ++fr)
      #pragma unroll
      for (int r = 0; r < 4; ++r) {
        int i = ib + wy * 32 + fr * 16 + q * 4 + r;
        zb[(size_t)i * KP + e] = f2bf(acc[fr][fc][r] + bv);
      }
  }
}

// GEMM2 + argmax, barrier-free j-stream.
// Block: 256 thr / 4 waves. i-tile = 128 (zb resident LDS, packet layout
// [kp 0..35][i 0..127] x 16B = 72KB). Each wave: 64 j per j-step x 128 i,
// A-frags (cb2) loaded global->register. grid (8 jsplit, 64 iblock);
// jsplit streams 2048 j in 8 j-steps of 256 (4 waves x 64 j).
// cand[jsplit][i] = packed (cvt(score*2^22)<<14)|(16383-j).
__global__ __launch_bounds__(256, 2)
void k_gemm2(const unsigned short* __restrict__ cb2, const unsigned short* __restrict__ zb,
             int* __restrict__ cand) {
  __shared__ __align__(16) uint8_t ldsB[4608 * 16];  // 72 KB
  __shared__ int csh[4][128];
  const int t = threadIdx.x, w = t >> 6, l = t & 63;
  const int l15 = l & 15, q = l >> 4;
  const int jb = blockIdx.x * 2048, ib = blockIdx.y * 128;
  // stage zb tile once: packet P -> i = P&127, kp = P>>7
  #pragma unroll
  for (int r = 0; r < 18; ++r) {
    int P = t + 256 * r;
    gl2lds16(zb + (size_t)(ib + (P & 127)) * KP + (P >> 7) * 8, ldsB + P * 16);
  }
  int rbest[8];
  #pragma unroll
  for (int fc = 0; fc < 8; ++fc) rbest[fc] = (int)0x80000000;
  __syncthreads();
  #pragma unroll 1
  for (int js = 0; js < 8; ++js) {
    const int jw = jb + js * 256 + w * 64;  // this wave's 64-j base
    const unsigned short* arow = cb2 + (size_t)(jw + l15) * KP + q * 8;
    f32x4 acc[4][8] = {};  // [fr j][fc i]
    #pragma unroll
    for (int ks = 0; ks < 9; ++ks) {
      s16x8 a[4];
      #pragma unroll
      for (int fr = 0; fr < 4; ++fr)
        a[fr] = *(const s16x8*)(arow + fr * 16 * KP + ks * 32);
      #pragma unroll
      for (int fc = 0; fc < 8; ++fc) {
        s16x8 b = *(const s16x8*)(ldsB + (size_t)((ks * 4 + q) * 128 + fc * 16 + l15) * 16);
        #pragma unroll
        for (int fr = 0; fr < 4; ++fr)
          acc[fr][fc] = __builtin_amdgcn_mfma_f32_16x16x32_bf16(a[fr], b, acc[fr][fc], 0, 0, 0);
      }
    }
    // fold scores into running best: j = jw + fr*16 + q*4 + r
    const int encq = 16383 - (jw + q * 4);
    #pragma unroll
    for (int fc = 0; fc < 8; ++fc) {
      int bb = rbest[fc];
      #pragma unroll
      for (int fr = 0; fr < 4; ++fr)
        #pragma unroll
        for (int r = 0; r < 4; ++r) {
          int si = (int)(acc[fr][fc][r] * SCALE);  // |score|*2^22 < 2^17
          int p = (int)(((unsigned)si << 14) | (unsigned)(encq - fr * 16 - r));
          bb = p > bb ? p : bb;
        }
      rbest[fc] = bb;
    }
  }
  // reduce over q (16-lane groups hold same i, different j)
  #pragma unroll
  for (int fc = 0; fc < 8; ++fc) {
    int bb = rbest[fc];
    bb = max(bb, __shfl_xor(bb, 16, 64));
    bb = max(bb, __shfl_xor(bb, 32, 64));
    if (l < 16) csh[w][fc * 16 + l] = bb;
  }
  __syncthreads();
  if (t < 128) {
    int m0 = max(max(csh[0][t], csh[1][t]), max(csh[2][t], csh[3][t]));
    cand[(size_t)blockIdx.x * 8192 + ib + t] = m0;
  }
}

// Fused argmin + loss + output gather. 128 blocks x 256 thr; block = (b, s0)
// covering 64 rows. dist_i = ||z_i||^2 - 2*score_i.
__global__ void k_final(const unsigned short* __restrict__ zb, const int* __restrict__ cand,
                        const float* __restrict__ cbk, float* __restrict__ lossw,
                        float* __restrict__ out) {
  __shared__ int lidx[64];
  __shared__ float ps[4];
  int blk = blockIdx.x, t = threadIdx.x;
  int b = blk >> 4, s0 = (blk & 15) * 64;
  int row = t >> 2, c = t & 3;
  int gi = b * 1024 + s0 + row;
  // ||z||^2 partial over 64 bf16 elems (cols 0..255 only)
  const unsigned short* zrow = zb + (size_t)gi * KP + c * 64;
  float ss = 0.0f;
  #pragma unroll
  for (int k = 0; k < 64; k += 4) {
    ushort4 v = *(const ushort4*)(zrow + k);
    float a0 = bf2f(v.x), a1 = bf2f(v.y), a2 = bf2f(v.z), a3 = bf2f(v.w);
    ss += a0 * a0 + a1 * a1 + a2 * a2 + a3 * a3;
  }
  // argmax partial over 8 jsplit partials
  int best = (int)0x80000000;
  #pragma unroll
  for (int k = 0; k < 2; ++k) {
    int v = cand[(size_t)(c + 4 * k) * 8192 + gi];
    best = v > best ? v : best;
  }
  best = max(best, __shfl_xor(best, 1, 64));
  best = max(best, __shfl_xor(best, 2, 64));
  ss += __shfl_xor(ss, 1, 64);
  ss += __shfl_xor(ss, 2, 64);
  float dist = 0.0f;
  if (c == 0) {
    lidx[row] = 16383 - (best & 0x3FFF);
    dist = ss - 2.0f * (float)(best >> 14) * (1.0f / SCALE);
  }
  float v = dist;
  #pragma unroll
  for (int m = 32; m; m >>= 1) v += __shfl_down(v, m, 64);
  if ((t & 63) == 0) ps[t >> 6] = v;
  __syncthreads();
  if (t == 0) {
    float part = ps[0] + ps[1] + ps[2] + ps[3];
    atomicAdd(lossw, part);
    __threadfence();
    int cnt = atomicAdd((int*)lossw + 1, 1);
    if (cnt == 127) {
      __threadfence();
      float total = atomicAdd(lossw, 0.0f);
      out[2097152] = 1.25f * total * (1.0f / 2097152.0f);
    }
  }
  // gather z_q: out[b][e][s0+sl] = cbk[lidx[sl]][e]
  int sl = t & 63, e0 = t >> 6;
  size_t ob = (size_t)b * 262144 + s0 + sl;
  size_t crow = (size_t)lidx[sl] * 256;
  for (int e = e0; e < 256; e += 4)
    out[ob + (size_t)e * 1024] = cbk[crow + e];
}

extern "C" void kernel_launch(void* const* d_in, const int* in_sizes, int n_in,
                              void* d_out, int out_size, void* d_ws, size_t ws_size,
                              hipStream_t stream) {
  const float* feats  = (const float*)d_in[0];
  const float* conv_w = (const float*)d_in[1];
  const float* conv_b = (const float*)d_in[2];
  const float* cbk    = (const float*)d_in[3];
  float* out = (float*)d_out;
  char* ws = (char*)d_ws;
  // workspace layout (bytes), ~31.7 MB total
  unsigned short* featsT = (unsigned short*)(ws);                  // 16,777,216
  unsigned short* W2     = (unsigned short*)(ws + 16777216);       //    524,288
  unsigned short* cb2    = (unsigned short*)(ws + 17301504);       //  9,437,184
  unsigned short* zb     = (unsigned short*)(ws + 26738688);       //  4,718,592
  int*            cand   = (int*)(ws + 31457280);                  //    262,144
  float*          lossw  = (float*)(ws + 31719424);                //        256

  k_prep<<<24832, 256, 0, stream>>>(cbk, conv_w, feats, cb2, W2, featsT, zb, lossw);
  k_gemm1<<<dim3(4, 128), 256, 0, stream>>>(featsT, W2, conv_b, zb);
  k_gemm2<<<dim3(8, 64), 256, 0, stream>>>(cb2, zb, cand);
  k_final<<<128, 256, 0, stream>>>(zb, cand, cbk, lossw, out);
}

// Round 5
// 255.042 us; speedup vs baseline: 1.4771x; 1.4771x over previous
//
#include <hip/hip_runtime.h>
#include <hip/hip_bf16.h>
#include <stdint.h>

// Problem: feats[8,1024,32,32]f32, conv_w[256,1024]f32, conv_b[256]f32,
// codebook[16384,256]f32 -> z_q[8,256,32,32]f32 (2097152) + loss scalar.
//
// Round-5 design:
//  - gemm2 j-stream, spill-proof: wave tile 64j x 64i (acc=64 VGPR),
//    block 128i (zb in LDS, 1 barrier), 512 j per block (4 j-steps x 128),
//    grid (32 jsplit, 64 ib) -> XCD-pinned 1.18 MB cb2 slice per XCD
//  - loss from packed best score: dist_i = ||z_i||^2 - 2*score_i

typedef float f32x4 __attribute__((ext_vector_type(4)));
typedef short s16x8 __attribute__((ext_vector_type(8)));

#define KP 288            // padded K (256 data + col256 bias-fold + 31 pad)
#define SCALE 4194304.0f  // 2^22

__device__ __forceinline__ void gl2lds16(const void* g, void* l) {
  __builtin_amdgcn_global_load_lds(
      (const __attribute__((address_space(1))) void*)g,
      (__attribute__((address_space(3))) void*)l, 16, 0, 0);
}

__device__ __forceinline__ unsigned short f2bf(float f) {
  unsigned u = __float_as_uint(f);
  u = u + 0x7FFFu + ((u >> 16) & 1u);
  return (unsigned short)(u >> 16);
}
__device__ __forceinline__ float bf2f(unsigned short u) {
  return __uint_as_float(((unsigned)u) << 16);
}

// Fused prep. Blocks [0,16384): codebook -> cb2 bf16 [16384][288], col256 =
// -0.5||e||^2, pad 0; zb pad cols for rows<8192. [16384,16640): conv_w -> W2.
// [16640,24832): feats transpose -> featsT bf16 [8192][1024].
__global__ void k_prep(const float* __restrict__ cbk, const float* __restrict__ Wsrc,
                       const float* __restrict__ feats,
                       unsigned short* __restrict__ cb2, unsigned short* __restrict__ W2,
                       unsigned short* __restrict__ At, unsigned short* __restrict__ zb,
                       float* __restrict__ lossw) {
  __shared__ float tile[32][33];
  __shared__ float ps[4];
  int blk = blockIdx.x, t = threadIdx.x;
  if (blk == 0 && t < 2) ((int*)lossw)[t] = 0;
  if (blk < 16384) {
    int j = blk;
    float v = cbk[(size_t)j * 256 + t];
    cb2[(size_t)j * KP + t] = f2bf(v);
    float s = v * v;
    #pragma unroll
    for (int m = 32; m; m >>= 1) s += __shfl_down(s, m, 64);
    if ((t & 63) == 0) ps[t >> 6] = s;
    __syncthreads();
    if (t == 0) cb2[(size_t)j * KP + 256] = f2bf(-0.5f * (ps[0] + ps[1] + ps[2] + ps[3]));
    if (t >= 1 && t < 32) cb2[(size_t)j * KP + 256 + t] = 0;
    if (j < 8192) {
      if (t == 0) zb[(size_t)j * KP + 256] = 0x3F80;  // 1.0 bf16
      if (t >= 1 && t < 32) zb[(size_t)j * KP + 256 + t] = 0;
    }
  } else if (blk < 16640) {
    int e = blk - 16384;
    #pragma unroll
    for (int k = 0; k < 4; ++k) {
      int c = t + k * 256;
      W2[(size_t)e * 1024 + c] = f2bf(Wsrc[(size_t)e * 1024 + c]);
    }
  } else {
    int id = blk - 16640;
    int b = id >> 10, c0 = ((id >> 5) & 31) * 32, s0 = (id & 31) * 32;
    int tc = t >> 5, ts = t & 31;
    #pragma unroll
    for (int k = 0; k < 4; ++k)
      tile[tc + k * 8][ts] = feats[((size_t)b * 1024 + c0 + tc + k * 8) * 1024 + s0 + ts];
    __syncthreads();
    #pragma unroll
    for (int k = 0; k < 4; ++k) {
      int sr = tc + k * 8, cw = ts;
      At[(size_t)(b * 1024 + s0 + sr) * 1024 + c0 + cw] = f2bf(tile[cw][sr]);
    }
  }
}

// GEMM1: z[i][e] = sum_c feats[i][c]*W[e][c] + b[e] (K=1024 bf16) -> zb [i][288].
// BM=BN=64, 4 waves 2x2 (wave 32x32), grid (4,128)
__global__ __launch_bounds__(256, 2)
void k_gemm1(const unsigned short* __restrict__ At, const unsigned short* __restrict__ Bw,
             const float* __restrict__ bias, unsigned short* __restrict__ zb) {
  __shared__ __align__(16) uint8_t lds[1024 * 16];
  uint8_t* ldsA = lds;
  uint8_t* ldsB = lds + 512 * 16;
  const int t = threadIdx.x, w = t >> 6, l = t & 63;
  const int wy = w >> 1, wx = w & 1, l15 = l & 15, q = l >> 4;
  const int ib = blockIdx.y * 64, eb = blockIdx.x * 64;
  f32x4 acc[2][2] = {};
  for (int kt = 0; kt < 16; ++kt) {
    int c0 = kt * 64;
    __syncthreads();
    #pragma unroll
    for (int r = 0; r < 2; ++r) {
      int P = t + 256 * r;  // kp = P>>6, m = P&63; LDS layout [kp][m]
      gl2lds16(At + (size_t)(ib + (P & 63)) * 1024 + c0 + (P >> 6) * 8, ldsA + P * 16);
    }
    #pragma unroll
    for (int r = 0; r < 2; ++r) {
      int P = t + 256 * r;
      gl2lds16(Bw + (size_t)(eb + (P & 63)) * 1024 + c0 + (P >> 6) * 8, ldsB + P * 16);
    }
    __syncthreads();
    #pragma unroll
    for (int s = 0; s < 2; ++s) {
      s16x8 a[2], b[2];
      #pragma unroll
      for (int fr = 0; fr < 2; ++fr)
        a[fr] = *(const s16x8*)(ldsA + ((s * 4 + q) * 64 + wy * 32 + fr * 16 + l15) * 16);
      #pragma unroll
      for (int fc = 0; fc < 2; ++fc)
        b[fc] = *(const s16x8*)(ldsB + ((s * 4 + q) * 64 + wx * 32 + fc * 16 + l15) * 16);
      #pragma unroll
      for (int fr = 0; fr < 2; ++fr)
        #pragma unroll
        for (int fc = 0; fc < 2; ++fc)
          acc[fr][fc] = __builtin_amdgcn_mfma_f32_16x16x32_bf16(a[fr], b[fc], acc[fr][fc], 0, 0, 0);
    }
  }
  #pragma unroll
  for (int fc = 0; fc < 2; ++fc) {
    int e = eb + wx * 32 + fc * 16 + l15;
    float bv = bias[e];
    #pragma unroll
    for (int fr = 0; fr < 2; ++fr)
      #pragma unroll
      for (int r = 0; r < 4; ++r) {
        int i = ib + wy * 32 + fr * 16 + q * 4 + r;
        zb[(size_t)i * KP + e] = f2bf(acc[fr][fc][r] + bv);
      }
  }
}

// GEMM2 + argmax, j-stream. Block: 256 thr / 4 waves (wy 2 x wx 2), wave tile
// 64j x 64i, acc = 16 f32x4 = 64 VGPR (no spills). zb tile 128i resident in
// LDS (72 KB packet layout [kp 0..35][i 0..127]x16B, one barrier). Each block
// streams 512 j in 4 j-steps of 128 (wy halves). A (cb2) loads go
// global->register, L2-served via XCD pinning: grid (32 jsplit, 64 ib),
// XCD = linear%8 -> 4 jsplits/XCD = 1.18 MB resident slice.
// cand[jsplit][i] = packed (cvt(score*2^22)<<14)|(16383-j).
__global__ __launch_bounds__(256, 2)
void k_gemm2(const unsigned short* __restrict__ cb2, const unsigned short* __restrict__ zb,
             int* __restrict__ cand) {
  __shared__ __align__(16) uint8_t ldsB[4608 * 16];  // 72 KB
  __shared__ int csh[2][128];
  const int t = threadIdx.x, w = t >> 6, l = t & 63;
  const int wy = w >> 1, wx = w & 1, l15 = l & 15, q = l >> 4;
  const int jb = blockIdx.x * 512, ib = blockIdx.y * 128;
  // stage zb tile once: packet P -> i = P&127, kp = P>>7
  #pragma unroll
  for (int r = 0; r < 18; ++r) {
    int P = t + 256 * r;
    gl2lds16(zb + (size_t)(ib + (P & 127)) * KP + (P >> 7) * 8, ldsB + P * 16);
  }
  int rbest[4];
  #pragma unroll
  for (int fc = 0; fc < 4; ++fc) rbest[fc] = (int)0x80000000;
  __syncthreads();
  #pragma unroll 1
  for (int js = 0; js < 4; ++js) {
    const int jw = jb + js * 128 + wy * 64;  // this wave's 64-j base
    const unsigned short* arow = cb2 + (size_t)(jw + l15) * KP + q * 8;
    f32x4 acc[4][4] = {};  // [fr j][fc i]
    #pragma unroll
    for (int ks = 0; ks < 9; ++ks) {
      s16x8 a[4];
      #pragma unroll
      for (int fr = 0; fr < 4; ++fr)
        a[fr] = *(const s16x8*)(arow + fr * 16 * KP + ks * 32);
      #pragma unroll
      for (int fc = 0; fc < 4; ++fc) {
        s16x8 b = *(const s16x8*)(ldsB + (size_t)((ks * 4 + q) * 128 + wx * 64 + fc * 16 + l15) * 16);
        #pragma unroll
        for (int fr = 0; fr < 4; ++fr)
          acc[fr][fc] = __builtin_amdgcn_mfma_f32_16x16x32_bf16(a[fr], b, acc[fr][fc], 0, 0, 0);
      }
    }
    // fold scores: j = jw + fr*16 + q*4 + r
    const int encq = 16383 - (jw + q * 4);
    #pragma unroll
    for (int fc = 0; fc < 4; ++fc) {
      int bb = rbest[fc];
      #pragma unroll
      for (int fr = 0; fr < 4; ++fr)
        #pragma unroll
        for (int r = 0; r < 4; ++r) {
          int si = (int)(acc[fr][fc][r] * SCALE);  // |score|*2^22 < 2^17
          int p = (int)(((unsigned)si << 14) | (unsigned)(encq - fr * 16 - r));
          bb = p > bb ? p : bb;
        }
      rbest[fc] = bb;
    }
  }
  // reduce over q (16-lane groups: same i, different j)
  #pragma unroll
  for (int fc = 0; fc < 4; ++fc) {
    int bb = rbest[fc];
    bb = max(bb, __shfl_xor(bb, 16, 64));
    bb = max(bb, __shfl_xor(bb, 32, 64));
    if (l < 16) csh[wy][wx * 64 + fc * 16 + l] = bb;
  }
  __syncthreads();
  if (t < 128) {
    int m0 = max(csh[0][t], csh[1][t]);
    cand[(size_t)blockIdx.x * 8192 + ib + t] = m0;
  }
}

// Fused argmin + loss + output gather. 128 blocks x 256 thr; block = (b, s0)
// covering 64 rows. dist_i = ||z_i||^2 - 2*score_i.
__global__ void k_final(const unsigned short* __restrict__ zb, const int* __restrict__ cand,
                        const float* __restrict__ cbk, float* __restrict__ lossw,
                        float* __restrict__ out) {
  __shared__ int lidx[64];
  __shared__ float ps[4];
  int blk = blockIdx.x, t = threadIdx.x;
  int b = blk >> 4, s0 = (blk & 15) * 64;
  int row = t >> 2, c = t & 3;
  int gi = b * 1024 + s0 + row;
  // ||z||^2 partial over 64 bf16 elems (cols 0..255 only)
  const unsigned short* zrow = zb + (size_t)gi * KP + c * 64;
  float ss = 0.0f;
  #pragma unroll
  for (int k = 0; k < 64; k += 4) {
    ushort4 v = *(const ushort4*)(zrow + k);
    float a0 = bf2f(v.x), a1 = bf2f(v.y), a2 = bf2f(v.z), a3 = bf2f(v.w);
    ss += a0 * a0 + a1 * a1 + a2 * a2 + a3 * a3;
  }
  // argmax over 32 jsplit partials
  int best = (int)0x80000000;
  #pragma unroll
  for (int k = 0; k < 8; ++k) {
    int v = cand[(size_t)(c + 4 * k) * 8192 + gi];
    best = v > best ? v : best;
  }
  best = max(best, __shfl_xor(best, 1, 64));
  best = max(best, __shfl_xor(best, 2, 64));
  ss += __shfl_xor(ss, 1, 64);
  ss += __shfl_xor(ss, 2, 64);
  float dist = 0.0f;
  if (c == 0) {
    lidx[row] = 16383 - (best & 0x3FFF);
    dist = ss - 2.0f * (float)(best >> 14) * (1.0f / SCALE);
  }
  float v = dist;
  #pragma unroll
  for (int m = 32; m; m >>= 1) v += __shfl_down(v, m, 64);
  if ((t & 63) == 0) ps[t >> 6] = v;
  __syncthreads();
  if (t == 0) {
    float part = ps[0] + ps[1] + ps[2] + ps[3];
    atomicAdd(lossw, part);
    __threadfence();
    int cnt = atomicAdd((int*)lossw + 1, 1);
    if (cnt == 127) {
      __threadfence();
      float total = atomicAdd(lossw, 0.0f);
      out[2097152] = 1.25f * total * (1.0f / 2097152.0f);
    }
  }
  // gather z_q: out[b][e][s0+sl] = cbk[lidx[sl]][e]
  int sl = t & 63, e0 = t >> 6;
  size_t ob = (size_t)b * 262144 + s0 + sl;
  size_t crow = (size_t)lidx[sl] * 256;
  for (int e = e0; e < 256; e += 4)
    out[ob + (size_t)e * 1024] = cbk[crow + e];
}

extern "C" void kernel_launch(void* const* d_in, const int* in_sizes, int n_in,
                              void* d_out, int out_size, void* d_ws, size_t ws_size,
                              hipStream_t stream) {
  const float* feats  = (const float*)d_in[0];
  const float* conv_w = (const float*)d_in[1];
  const float* conv_b = (const float*)d_in[2];
  const float* cbk    = (const float*)d_in[3];
  float* out = (float*)d_out;
  char* ws = (char*)d_ws;
  // workspace layout (bytes), ~32.5 MB total
  unsigned short* featsT = (unsigned short*)(ws);                  // 16,777,216
  unsigned short* W2     = (unsigned short*)(ws + 16777216);       //    524,288
  unsigned short* cb2    = (unsigned short*)(ws + 17301504);       //  9,437,184
  unsigned short* zb     = (unsigned short*)(ws + 26738688);       //  4,718,592
  int*            cand   = (int*)(ws + 31457280);                  //  1,048,576
  float*          lossw  = (float*)(ws + 32505856);                //        256

  k_prep<<<24832, 256, 0, stream>>>(cbk, conv_w, feats, cb2, W2, featsT, zb, lossw);
  k_gemm1<<<dim3(4, 128), 256, 0, stream>>>(featsT, W2, conv_b, zb);
  k_gemm2<<<dim3(32, 64), 256, 0, stream>>>(cb2, zb, cand);
  k_final<<<128, 256, 0, stream>>>(zb, cand, cbk, lossw, out);
}